// Round 10
// baseline (149.287 us; speedup 1.0000x reference)
//
#include <hip/hip_runtime.h>
#include <stdint.h>

#define B_      32
#define T_      1024
#define D_      512
#define MAXLEN_ 8192

typedef float f4 __attribute__((ext_vector_type(4)));

// ---------------------------------------------------------------------------
// Kernel 1: per-batch shuffle-based inclusive scan (1 barrier) + DIRECT
// scatter of the expansion index: thread t owns output positions
// [cum_prev, cum) and writes t there; tail [mel, 8192) gets -1 (disjoint
// ranges -> no second barrier). mel_len -> tail of d_out.
// ---------------------------------------------------------------------------
__global__ void lr_scan_scatter_kernel(const int* __restrict__ dur,
                                       int* __restrict__ idx,
                                       float* __restrict__ mel_out) {
    int b    = blockIdx.x;
    int t    = threadIdx.x;        // 0..1023
    int lane = t & 63;
    int wave = t >> 6;             // 0..15

    int d = dur[b * T_ + t];

    // wave-level inclusive scan (no barriers)
    int v = d;
    #pragma unroll
    for (int off = 1; off < 64; off <<= 1) {
        int n = __shfl_up(v, off, 64);
        if (lane >= off) v += n;
    }

    __shared__ int wsum[16];
    if (lane == 63) wsum[wave] = v;
    __syncthreads();

    int off = 0, tot = 0;
    #pragma unroll
    for (int w = 0; w < 16; ++w) {
        int s = wsum[w];
        off += (w < wave) ? s : 0;
        tot += s;
    }
    int cum  = v + off;            // inclusive cumsum at position t
    int cump = cum - d;            // exclusive

    if (t == T_ - 1) mel_out[b] = (float)tot;

    int* row = idx + b * MAXLEN_;
    for (int j = cump; j < cum; ++j) row[j] = t;              // d in [0,8)
    for (int p = tot + t; p < MAXLEN_; p += T_) row[p] = -1;  // masked tail
}

// ---------------------------------------------------------------------------
// Kernel 2: LOW-OCCUPANCY streaming gather. 512 blocks x 256 threads
// (2 blocks/CU, 8 waves/CU ~= 25% occupancy -- the regime where the 6.7TB/s
// rocclr fills live: few, long-lived, orderly per-channel write streams).
// Each block owns 512 CONTIGUOUS rows (1MB of output) streamed in 64
// iterations of the R5 inner shape (8 rows/iter, half-wave per row, 4 f4
// strided = 64B/lane). The block's 512 idx entries are staged into LDS
// up-front, removing the idx->x dependent chain from the loop.
// Blocks never straddle batches (8192/512 = 16).
// out[b, p, :] = (idx >= 0) ? x[b, idx, :] : 0
// ---------------------------------------------------------------------------
__global__ __launch_bounds__(256) void lr_gather_kernel(
        const f4* __restrict__ x,
        const int* __restrict__ idx,
        f4* __restrict__ out) {
    __shared__ int sidx[512];
    int base = (int)blockIdx.x * 512;            // 512 blocks x 512 rows

    sidx[threadIdx.x]       = idx[base + (int)threadIdx.x];
    sidx[threadIdx.x + 256] = idx[base + (int)threadIdx.x + 256];
    __syncthreads();

    int h = (int)(threadIdx.x >> 5);             // half-wave id, 0..7
    int c = (int)(threadIdx.x & 31);             // f4 col base
    int b = base >> 13;                          // batch (uniform per block)
    const f4* xb = x + (((long long)b * T_) << 7);

    for (int r = 0; r < 64; ++r) {
        int row = base + r * 8 + h;
        int tt  = sidx[r * 8 + h];               // LDS broadcast, no HBM dep
        f4* o = out + ((((long long)row) << 7) + c);     // 128 f4 per row
        if (tt >= 0) {
            const f4* src = xb + ((((long long)tt) << 7) + c);
            o[0]  = src[0];
            o[32] = src[32];
            o[64] = src[64];
            o[96] = src[96];
        } else {
            f4 z = (f4){0.f, 0.f, 0.f, 0.f};
            o[0]  = z;
            o[32] = z;
            o[64] = z;
            o[96] = z;
        }
    }
}

// ---------------------------------------------------------------------------
// Fallback (ws too small for the 1MB idx array): cum in ws + fused search.
// ---------------------------------------------------------------------------
__global__ void lr_cumsum_kernel(const int* __restrict__ dur,
                                 int* __restrict__ cum,
                                 float* __restrict__ mel_out) {
    int b = blockIdx.x;
    int t = threadIdx.x;
    __shared__ int s[T_];
    s[t] = dur[b * T_ + t];
    __syncthreads();
    #pragma unroll
    for (int off = 1; off < T_; off <<= 1) {
        int v = (t >= off) ? s[t - off] : 0;
        __syncthreads();
        s[t] += v;
        __syncthreads();
    }
    cum[b * T_ + t] = s[t];
    if (t == T_ - 1) mel_out[b] = (float)s[t];
}

__global__ void lr_gather_fused_kernel(const f4* __restrict__ x,
                                       const int* __restrict__ cum,
                                       f4* __restrict__ out) {
    const long long total = (long long)B_ * MAXLEN_ * (D_ / 4);
    const long long stride = (long long)gridDim.x * blockDim.x;
    for (long long gid = (long long)blockIdx.x * blockDim.x + threadIdx.x;
         gid < total; gid += stride) {
        int row = (int)(gid >> 7);
        int c   = (int)(gid & 127);
        int b   = row >> 13;
        int p   = row & (MAXLEN_ - 1);
        const int* cm = cum + b * T_;
        int mel = cm[T_ - 1];
        f4 v = (f4){0.f, 0.f, 0.f, 0.f};
        if (p < mel) {
            int lo = 0, hi = T_;
            #pragma unroll
            for (int it = 0; it < 10; ++it) {
                int mid = (lo + hi) >> 1;
                if (cm[mid] <= p) lo = mid + 1; else hi = mid;
            }
            v = x[(((long long)(b * T_ + lo)) << 7) | c];
        }
        out[gid] = v;
    }
}

extern "C" void kernel_launch(void* const* d_in, const int* in_sizes, int n_in,
                              void* d_out, int out_size, void* d_ws, size_t ws_size,
                              hipStream_t stream) {
    const float* x   = (const float*)d_in[0];
    const int*   dur = (const int*)d_in[1];   // harness converts integers to int32
    // d_in[2] = max_len scalar (8192) -- compile-time constant here.

    float* out     = (float*)d_out;
    float* mel_out = out + (size_t)B_ * MAXLEN_ * D_;   // output 1 tail

    const size_t need_idx = (size_t)B_ * MAXLEN_ * sizeof(int);   // 1 MB

    if (ws_size >= need_idx) {
        int* idx = (int*)d_ws;
        lr_scan_scatter_kernel<<<B_, T_, 0, stream>>>(dur, idx, mel_out);
        // 262144 output rows / 512 rows per block = 512 blocks (2 per CU)
        lr_gather_kernel<<<(B_ * MAXLEN_) / 512, 256, 0, stream>>>(
            (const f4*)x, idx, (f4*)out);
    } else {
        int* cum = (int*)d_ws;                            // 128 KB
        lr_cumsum_kernel<<<B_, T_, 0, stream>>>(dur, cum, mel_out);
        lr_gather_fused_kernel<<<4096, 256, 0, stream>>>((const f4*)x, cum,
                                                         (f4*)out);
    }
}

// Round 11
// 126.729 us; speedup vs baseline: 1.1780x; 1.1780x over previous
//
#include <hip/hip_runtime.h>
#include <stdint.h>

#define B_      32
#define T_      1024
#define D_      512
#define MAXLEN_ 8192

typedef float f4 __attribute__((ext_vector_type(4)));

// ---------------------------------------------------------------------------
// Kernel 1: per-batch shuffle-based inclusive scan (1 barrier) + DIRECT
// scatter of the expansion index: thread t owns output positions
// [cum_prev, cum) and writes t there; tail [mel, 8192) gets -1 (disjoint
// ranges -> no second barrier). mel_len -> tail of d_out.
// ---------------------------------------------------------------------------
__global__ void lr_scan_scatter_kernel(const int* __restrict__ dur,
                                       int* __restrict__ idx,
                                       float* __restrict__ mel_out) {
    int b    = blockIdx.x;
    int t    = threadIdx.x;        // 0..1023
    int lane = t & 63;
    int wave = t >> 6;             // 0..15

    int d = dur[b * T_ + t];

    // wave-level inclusive scan (no barriers)
    int v = d;
    #pragma unroll
    for (int off = 1; off < 64; off <<= 1) {
        int n = __shfl_up(v, off, 64);
        if (lane >= off) v += n;
    }

    __shared__ int wsum[16];
    if (lane == 63) wsum[wave] = v;
    __syncthreads();

    int off = 0, tot = 0;
    #pragma unroll
    for (int w = 0; w < 16; ++w) {
        int s = wsum[w];
        off += (w < wave) ? s : 0;
        tot += s;
    }
    int cum  = v + off;            // inclusive cumsum at position t
    int cump = cum - d;            // exclusive

    if (t == T_ - 1) mel_out[b] = (float)tot;

    int* row = idx + b * MAXLEN_;
    for (int j = cump; j < cum; ++j) row[j] = t;              // d in [0,8)
    for (int p = tot + t; p < MAXLEN_; p += T_) row[p] = -1;  // masked tail
}

// ---------------------------------------------------------------------------
// Kernels 2a/2b: STREAM-PURITY SPLIT of the R5 winner (32768 blocks, 8 rows/
// block, half-wave per row, 4xf4 = 64B/lane, XCD-chunked swizzle).
// Per batch, valid rows [0,mel) and masked rows [mel,8192) are two large
// contiguous segments, so splitting costs only an idx re-read (1MB):
//   2a: pure copy dispatch  (masked half-waves exit after the idx load)
//   2b: pure zero-fill dispatch (valid half-waves exit) -- fill-rate regime.
// ---------------------------------------------------------------------------
__global__ __launch_bounds__(256) void lr_copy_kernel(
        const f4* __restrict__ x,
        const int* __restrict__ idx,
        f4* __restrict__ out) {
    unsigned bid   = blockIdx.x;
    unsigned chunk = gridDim.x >> 3;                 // 32768/8 = 4096
    unsigned nb    = (bid & 7) * chunk + (bid >> 3); // XCD-chunked swizzle

    int row = (int)(nb * 8) + (int)(threadIdx.x >> 5);   // 8 rows/block
    int c   = (int)(threadIdx.x & 31);                   // f4 col base
    int tt  = idx[row];
    if (tt < 0) return;                                  // masked: kernel 2b's job

    int b = row >> 13;                                   // MAXLEN_ = 2^13
    const f4* src = x + ((((long long)(b * T_ + tt)) << 7) + c);
    f4* o = out + ((((long long)row) << 7) + c);         // 128 f4 per row
    o[0]  = src[0];
    o[32] = src[32];
    o[64] = src[64];
    o[96] = src[96];
}

__global__ __launch_bounds__(256) void lr_zero_kernel(
        const int* __restrict__ idx,
        f4* __restrict__ out) {
    unsigned bid   = blockIdx.x;
    unsigned chunk = gridDim.x >> 3;
    unsigned nb    = (bid & 7) * chunk + (bid >> 3);

    int row = (int)(nb * 8) + (int)(threadIdx.x >> 5);
    int c   = (int)(threadIdx.x & 31);
    if (idx[row] >= 0) return;                           // valid: kernel 2a's job

    f4 z = (f4){0.f, 0.f, 0.f, 0.f};
    f4* o = out + ((((long long)row) << 7) + c);
    o[0]  = z;
    o[32] = z;
    o[64] = z;
    o[96] = z;
}

// ---------------------------------------------------------------------------
// Fallback (ws too small for the 1MB idx array): cum in ws + fused search.
// ---------------------------------------------------------------------------
__global__ void lr_cumsum_kernel(const int* __restrict__ dur,
                                 int* __restrict__ cum,
                                 float* __restrict__ mel_out) {
    int b = blockIdx.x;
    int t = threadIdx.x;
    __shared__ int s[T_];
    s[t] = dur[b * T_ + t];
    __syncthreads();
    #pragma unroll
    for (int off = 1; off < T_; off <<= 1) {
        int v = (t >= off) ? s[t - off] : 0;
        __syncthreads();
        s[t] += v;
        __syncthreads();
    }
    cum[b * T_ + t] = s[t];
    if (t == T_ - 1) mel_out[b] = (float)s[t];
}

__global__ void lr_gather_fused_kernel(const f4* __restrict__ x,
                                       const int* __restrict__ cum,
                                       f4* __restrict__ out) {
    const long long total = (long long)B_ * MAXLEN_ * (D_ / 4);
    const long long stride = (long long)gridDim.x * blockDim.x;
    for (long long gid = (long long)blockIdx.x * blockDim.x + threadIdx.x;
         gid < total; gid += stride) {
        int row = (int)(gid >> 7);
        int c   = (int)(gid & 127);
        int b   = row >> 13;
        int p   = row & (MAXLEN_ - 1);
        const int* cm = cum + b * T_;
        int mel = cm[T_ - 1];
        f4 v = (f4){0.f, 0.f, 0.f, 0.f};
        if (p < mel) {
            int lo = 0, hi = T_;
            #pragma unroll
            for (int it = 0; it < 10; ++it) {
                int mid = (lo + hi) >> 1;
                if (cm[mid] <= p) lo = mid + 1; else hi = mid;
            }
            v = x[(((long long)(b * T_ + lo)) << 7) | c];
        }
        out[gid] = v;
    }
}

extern "C" void kernel_launch(void* const* d_in, const int* in_sizes, int n_in,
                              void* d_out, int out_size, void* d_ws, size_t ws_size,
                              hipStream_t stream) {
    const float* x   = (const float*)d_in[0];
    const int*   dur = (const int*)d_in[1];   // harness converts integers to int32
    // d_in[2] = max_len scalar (8192) -- compile-time constant here.

    float* out     = (float*)d_out;
    float* mel_out = out + (size_t)B_ * MAXLEN_ * D_;   // output 1 tail

    const size_t need_idx = (size_t)B_ * MAXLEN_ * sizeof(int);   // 1 MB

    if (ws_size >= need_idx) {
        int* idx = (int*)d_ws;
        lr_scan_scatter_kernel<<<B_, T_, 0, stream>>>(dur, idx, mel_out);
        // 262144 output rows / 8 rows per block = 32768 blocks (mult of 8)
        int grid = (B_ * MAXLEN_) / 8;
        lr_copy_kernel<<<grid, 256, 0, stream>>>((const f4*)x, idx, (f4*)out);
        lr_zero_kernel<<<grid, 256, 0, stream>>>(idx, (f4*)out);
    } else {
        int* cum = (int*)d_ws;                            // 128 KB
        lr_cumsum_kernel<<<B_, T_, 0, stream>>>(dur, cum, mel_out);
        lr_gather_fused_kernel<<<4096, 256, 0, stream>>>((const f4*)x, cum,
                                                         (f4*)out);
    }
}

// Round 12
// 118.438 us; speedup vs baseline: 1.2605x; 1.0700x over previous
//
#include <hip/hip_runtime.h>
#include <stdint.h>

#define B_      32
#define T_      1024
#define D_      512
#define MAXLEN_ 8192

typedef float f4 __attribute__((ext_vector_type(4)));

// ---------------------------------------------------------------------------
// Kernel 1: per-batch shuffle-based inclusive scan (1 barrier) + DIRECT
// scatter of the expansion index: thread t owns output positions
// [cum_prev, cum) and writes t there; tail [mel, 8192) gets -1 (disjoint
// ranges -> no second barrier). mel_len -> tail of d_out.
// ---------------------------------------------------------------------------
__global__ void lr_scan_scatter_kernel(const int* __restrict__ dur,
                                       int* __restrict__ idx,
                                       float* __restrict__ mel_out) {
    int b    = blockIdx.x;
    int t    = threadIdx.x;        // 0..1023
    int lane = t & 63;
    int wave = t >> 6;             // 0..15

    int d = dur[b * T_ + t];

    // wave-level inclusive scan (no barriers)
    int v = d;
    #pragma unroll
    for (int off = 1; off < 64; off <<= 1) {
        int n = __shfl_up(v, off, 64);
        if (lane >= off) v += n;
    }

    __shared__ int wsum[16];
    if (lane == 63) wsum[wave] = v;
    __syncthreads();

    int off = 0, tot = 0;
    #pragma unroll
    for (int w = 0; w < 16; ++w) {
        int s = wsum[w];
        off += (w < wave) ? s : 0;
        tot += s;
    }
    int cum  = v + off;            // inclusive cumsum at position t
    int cump = cum - d;            // exclusive

    if (t == T_ - 1) mel_out[b] = (float)tot;

    int* row = idx + b * MAXLEN_;
    for (int j = cump; j < cum; ++j) row[j] = t;              // d in [0,8)
    for (int p = tot + t; p < MAXLEN_; p += T_) row[p] = -1;  // masked tail
}

// ---------------------------------------------------------------------------
// Kernel 2 (R5 winner, 118.8us): gather. 8 output rows per 256-thread block
// (half-wave per row, 4 f4 = 64B per lane, each store instruction = 512B
// contiguous per half-wave). XCD-chunked block swizzle keeps x-row reuse
// (~3.5 adjacent output rows per x row) inside one XCD's L2.
// Measured landscape (falsified alternatives): nt stores 2x write-amp (463us);
// 16 rows/block+batched idx 126us; 2048 persistent blocks 153us; 65536
// full-wave rows 124us; 512-block LDS-staged streaming 149us; copy/zero
// stream-purity split 127us. Mixed ~90%-write traffic runs at ~5.3TB/s vs
// 6.7TB/s pure fill -- that gap is the mixed-stream wall, not geometry.
// out[b, p, :] = (idx >= 0) ? x[b, idx, :] : 0
// ---------------------------------------------------------------------------
__global__ __launch_bounds__(256) void lr_gather_kernel(
        const f4* __restrict__ x,
        const int* __restrict__ idx,
        f4* __restrict__ out) {
    unsigned bid   = blockIdx.x;
    unsigned chunk = gridDim.x >> 3;                 // 32768/8 = 4096
    unsigned nb    = (bid & 7) * chunk + (bid >> 3); // XCD-chunked swizzle

    int row  = (int)(nb * 8) + (int)(threadIdx.x >> 5);  // 8 rows/block
    int colf = (int)(threadIdx.x & 31);                  // f4 col base
    int tt   = idx[row];

    f4* o = out + (((long long)row) << 7) + colf;        // 128 f4 per row
    if (tt >= 0) {
        int b = row >> 13;                               // MAXLEN_ = 2^13
        const f4* src = x + (((long long)(b * T_ + tt)) << 7) + colf;
        o[0]  = src[0];
        o[32] = src[32];
        o[64] = src[64];
        o[96] = src[96];
    } else {
        f4 z = (f4){0.f, 0.f, 0.f, 0.f};
        o[0]  = z;
        o[32] = z;
        o[64] = z;
        o[96] = z;
    }
}

// ---------------------------------------------------------------------------
// Fallback (ws too small for the 1MB idx array): cum in ws + fused search.
// ---------------------------------------------------------------------------
__global__ void lr_cumsum_kernel(const int* __restrict__ dur,
                                 int* __restrict__ cum,
                                 float* __restrict__ mel_out) {
    int b = blockIdx.x;
    int t = threadIdx.x;
    __shared__ int s[T_];
    s[t] = dur[b * T_ + t];
    __syncthreads();
    #pragma unroll
    for (int off = 1; off < T_; off <<= 1) {
        int v = (t >= off) ? s[t - off] : 0;
        __syncthreads();
        s[t] += v;
        __syncthreads();
    }
    cum[b * T_ + t] = s[t];
    if (t == T_ - 1) mel_out[b] = (float)s[t];
}

__global__ void lr_gather_fused_kernel(const f4* __restrict__ x,
                                       const int* __restrict__ cum,
                                       f4* __restrict__ out) {
    const long long total = (long long)B_ * MAXLEN_ * (D_ / 4);
    const long long stride = (long long)gridDim.x * blockDim.x;
    for (long long gid = (long long)blockIdx.x * blockDim.x + threadIdx.x;
         gid < total; gid += stride) {
        int row = (int)(gid >> 7);
        int c   = (int)(gid & 127);
        int b   = row >> 13;
        int p   = row & (MAXLEN_ - 1);
        const int* cm = cum + b * T_;
        int mel = cm[T_ - 1];
        f4 v = (f4){0.f, 0.f, 0.f, 0.f};
        if (p < mel) {
            int lo = 0, hi = T_;
            #pragma unroll
            for (int it = 0; it < 10; ++it) {
                int mid = (lo + hi) >> 1;
                if (cm[mid] <= p) lo = mid + 1; else hi = mid;
            }
            v = x[(((long long)(b * T_ + lo)) << 7) | c];
        }
        out[gid] = v;
    }
}

extern "C" void kernel_launch(void* const* d_in, const int* in_sizes, int n_in,
                              void* d_out, int out_size, void* d_ws, size_t ws_size,
                              hipStream_t stream) {
    const float* x   = (const float*)d_in[0];
    const int*   dur = (const int*)d_in[1];   // harness converts integers to int32
    // d_in[2] = max_len scalar (8192) -- compile-time constant here.

    float* out     = (float*)d_out;
    float* mel_out = out + (size_t)B_ * MAXLEN_ * D_;   // output 1 tail

    const size_t need_idx = (size_t)B_ * MAXLEN_ * sizeof(int);   // 1 MB

    if (ws_size >= need_idx) {
        int* idx = (int*)d_ws;
        lr_scan_scatter_kernel<<<B_, T_, 0, stream>>>(dur, idx, mel_out);
        // 262144 output rows / 8 rows per block = 32768 blocks (mult of 8)
        lr_gather_kernel<<<(B_ * MAXLEN_) / 8, 256, 0, stream>>>(
            (const f4*)x, idx, (f4*)out);
    } else {
        int* cum = (int*)d_ws;                            // 128 KB
        lr_cumsum_kernel<<<B_, T_, 0, stream>>>(dur, cum, mel_out);
        lr_gather_fused_kernel<<<4096, 256, 0, stream>>>((const f4*)x, cum,
                                                         (f4*)out);
    }
}